// Round 9
// baseline (755.740 us; speedup 1.0000x reference)
//
#include <hip/hip_runtime.h>
#include <cmath>
#include <stdint.h>

#define B_ 32
#define T_ 2048
#define H_ 1024

typedef __attribute__((ext_vector_type(8))) __bf16 bf16x8;
typedef __attribute__((ext_vector_type(4))) float f32x4;

__device__ inline void async_copy16(const void* g, void* l) {
    __builtin_amdgcn_global_load_lds((const __attribute__((address_space(1))) uint32_t*)g,
                                     (__attribute__((address_space(3))) uint32_t*)l, 16, 0, 0);
}

__device__ inline float fast_tanh(float x) {
    float e = __expf(2.f * x);
    return 1.f - 2.f / (e + 1.f);
}

__global__ __launch_bounds__(256) void zero_kernel(float* __restrict__ p, int n) {
    int i = blockIdx.x * 256 + threadIdx.x;
    if (i < n) p[i] = 0.f;
}

// fp32 -> bf16, 8 elements per thread; n must be a multiple of 2048 per grid sizing
__global__ __launch_bounds__(256) void convert_kernel(const float* __restrict__ in,
                                                      __bf16* __restrict__ out) {
    size_t i = (size_t)(blockIdx.x * 256 + threadIdx.x) * 8;
    const float4* p = (const float4*)(in + i);
    float4 v0 = p[0], v1 = p[1];
    bf16x8 o;
    o[0] = (__bf16)v0.x; o[1] = (__bf16)v0.y; o[2] = (__bf16)v0.z; o[3] = (__bf16)v0.w;
    o[4] = (__bf16)v1.x; o[5] = (__bf16)v1.y; o[6] = (__bf16)v1.z; o[7] = (__bf16)v1.w;
    *(bf16x8*)(out + i) = o;
}

// kq[b,h] = sum_j Wq[h,j]*dec[b,j] + bq[h] + bk[h]
__global__ __launch_bounds__(256) void q_kernel(const float* __restrict__ dec,
                                                const float* __restrict__ Wq,
                                                const float* __restrict__ bq,
                                                const float* __restrict__ bk,
                                                float* __restrict__ kq) {
    int b = blockIdx.x;
    int hc = blockIdx.y;
    __shared__ float ds[H_];
    for (int i = threadIdx.x; i < H_; i += 256) ds[i] = dec[b * H_ + i];
    __syncthreads();
    int h = hc * 256 + threadIdx.x;
    const float4* w = (const float4*)(Wq + (size_t)h * H_);
    float acc = 0.f;
#pragma unroll 8
    for (int j = 0; j < H_ / 4; j++) {
        float4 v = w[j];
        acc += v.x * ds[4 * j] + v.y * ds[4 * j + 1] + v.z * ds[4 * j + 2] + v.w * ds[4 * j + 3];
    }
    kq[b * H_ + h] = acc + bq[h] + bk[h];
}

// MFMA score GEMM: score[b,t] += sum_h Wout[h]*tanh(enc[t,:]·Wk[h,:] + kq[b,h])
//
// Round-8 occupancy diet: per-wave tile 128x64 -> 64x64 (acc 128 -> 64 regs)
// so TWO blocks/CU become register-feasible (target <=128 regs/thread).
// Block tile 256x128, BK=32, 8 waves as 4M x 2N; per-wave 4x4 16x16 frags.
// Same proven sync structure as the 265us kernel: 3 LDS buffers (now 24 KB
// each, 72 KB total -> 2 blocks/CU = 144 KB LDS), stage K-tile j+2 while
// computing tile j, ONE s_barrier + counted vmcnt(3) per boundary (3 staging
// loads/thread now). __launch_bounds__(512,4): 128-reg cap. r7 lesson: this
// spilled at ~216 regs needed; now ~120 needed -> safe squeeze. If counters
// show WRITE_SIZE >> 16MB, it spilled -> revert to r2 kernel.
__global__ __launch_bounds__(512, 4) void score_mfma(const __bf16* __restrict__ encb,
                                                     const __bf16* __restrict__ Wkb,
                                                     const float* __restrict__ kq,
                                                     const float* __restrict__ Wout,
                                                     float* __restrict__ score) {
    // per buffer: A = 1024 chunks (4 kg x 256 rows), B = 512 chunks (4 kg x
    // 128 rows); chunk = 16B. 24 KB/buffer.
    __shared__ __align__(16) __bf16 lds[3][12288];

    // XCD-aware bijective remap: gridDim=(8,256), lin = bx + 8*by, 2048 wgs.
    // xcd = lin%8; XCD x owns m-tiles [x*32, x*32+32) x all 8 n-blocks.
    const int lin = blockIdx.x + 8 * blockIdx.y;
    const int xcd = lin & 7;
    const int idx = lin >> 3;              // 0..255
    const int mblk = xcd * 32 + (idx >> 3);
    const int nblk = idx & 7;
    const int m0 = mblk * 256;
    const int h0 = nblk * 128;
    const int b = m0 >> 11;                // 2048 tokens per b; 256 | 2048

    const int tid = threadIdx.x;
    const int lane = tid & 63;
    const int w = tid >> 6;                // 0..7
    const int wm = w >> 1;                 // 0..3  (64-row quarter)
    const int wn = w & 1;                  // 0..1  (64-col half)
    const int q4 = lane >> 4, l15 = lane & 15;

    // ---- staging: 1536 chunks/buffer, 3 loads/thread ----
    // A instr0: chunk tid (kg=tid>>8 in {0,1}, row=tid&255); instr1: +512
    // chunks (kg+2). B instr2: chunk 1024+tid (kg=tid>>7, row=tid&127).
    const int rowA = tid & 255;
    const int kgA = tid >> 8;              // 0 or 1
    const __bf16* gA0 = encb + (size_t)(m0 + rowA) * H_ + kgA * 8;
    const __bf16* gA1 = gA0 + 16;          // kg+2
    const __bf16* gB0 = Wkb + (size_t)(h0 + (tid & 127)) * H_ + ((tid >> 7) & 3) * 8;
    const int sA0 = w * 512;               // wave-uniform LDS elem offsets
    const int sA1 = sA0 + 4096;            // +512 chunks
    const int sB0 = sA0 + 8192;            // B region at chunk 1024

    f32x4 acc[4][4];
#pragma unroll
    for (int i = 0; i < 4; i++)
#pragma unroll
        for (int jj = 0; jj < 4; jj++) acc[i][jj] = (f32x4){0.f, 0.f, 0.f, 0.f};

#define STAGE(jj)                                      \
    do {                                               \
        __bf16* Ld = &lds[(jj) % 3][0];                \
        const int kk = (jj) * 32;                      \
        async_copy16(gA0 + kk, Ld + sA0);              \
        async_copy16(gA1 + kk, Ld + sA1);              \
        async_copy16(gB0 + kk, Ld + sB0);              \
    } while (0)

    // prologue: tiles 0 and 1 in flight; wait tile 0 (3 newest may remain)
    STAGE(0);
    STAGE(1);
    asm volatile("s_waitcnt vmcnt(3)" ::: "memory");
    __builtin_amdgcn_s_barrier();
    __builtin_amdgcn_sched_barrier(0);

    for (int j = 0; j < 32; ++j) {
        if (j > 0) {
            if (j < 31) {
                asm volatile("s_waitcnt vmcnt(3)" ::: "memory");
            } else {
                asm volatile("s_waitcnt vmcnt(0)" ::: "memory");
            }
            __builtin_amdgcn_s_barrier();
            __builtin_amdgcn_sched_barrier(0);
        }
        const __bf16* L = &lds[j % 3][0];
        if (j < 30) STAGE(j + 2);

        // B frags: 4 x ds_read_b128 (chunk 1024 + q4*128 + wn*64 + nf*16 + l15)
        bf16x8 bfr[4];
#pragma unroll
        for (int nf = 0; nf < 4; nf++)
            bfr[nf] = *(const bf16x8*)(L + 8192 +
                                       (size_t)(q4 * 128 + wn * 64 + nf * 16 + l15) * 8);
        // A frags: rows wm*64 + mf*16 + l15, kg = q4
        bf16x8 afr[4];
#pragma unroll
        for (int mf = 0; mf < 4; mf++)
            afr[mf] = *(const bf16x8*)(L +
                                       (size_t)(q4 * 256 + wm * 64 + mf * 16 + l15) * 8);
        __builtin_amdgcn_s_setprio(1);
#pragma unroll
        for (int mf = 0; mf < 4; mf++)
#pragma unroll
            for (int nf = 0; nf < 4; nf++)
                acc[mf][nf] =
                    __builtin_amdgcn_mfma_f32_16x16x32_bf16(afr[mf], bfr[nf], acc[mf][nf], 0, 0, 0);
        __builtin_amdgcn_s_setprio(0);
    }
#undef STAGE

    // epilogue: per row, sum_h wout[h]*tanh(K + kq) over this wave's 64 columns
    float wv[4], kqv[4];
#pragma unroll
    for (int nf = 0; nf < 4; nf++) {
        int h = h0 + wn * 64 + nf * 16 + l15;
        wv[nf] = Wout[h];
        kqv[nf] = kq[b * H_ + h];
    }
#pragma unroll
    for (int mf = 0; mf < 4; mf++) {
#pragma unroll
        for (int r = 0; r < 4; r++) {
            float s = 0.f;
#pragma unroll
            for (int nf = 0; nf < 4; nf++)
                s += wv[nf] * fast_tanh(acc[mf][nf][r] + kqv[nf]);
#pragma unroll
            for (int m = 1; m < 16; m <<= 1) s += __shfl_xor(s, m, 64);
            if (l15 == 0)
                atomicAdd(&score[m0 + wm * 64 + mf * 16 + q4 * 4 + r], s);
        }
    }
}

// ---------- fp32 fallback score path (used only if ws too small) ----------
#define BK 32
#define ASTR 68
#define BSTR 132
__global__ __launch_bounds__(256) void score_fp32(const float* __restrict__ enc,
                                                  const float* __restrict__ Wk,
                                                  const float* __restrict__ kq,
                                                  const float* __restrict__ Wout,
                                                  float* __restrict__ score) {
    __shared__ __align__(16) float As[BK * ASTR];
    __shared__ __align__(16) float Bs[BK * BSTR];
    __shared__ float wout_s[128];
    __shared__ float kq_s[128];
    const int m0 = blockIdx.x * 64;
    const int h0 = blockIdx.y * 128;
    const int b = m0 >> 11;
    const int tid = threadIdx.x;
    const int tx = tid & 15;
    const int ty = tid >> 4;
    if (tid < 128) {
        wout_s[tid] = Wout[h0 + tid];
        kq_s[tid] = kq[b * H_ + h0 + tid];
    }
    float acc[4][8];
#pragma unroll
    for (int i = 0; i < 4; i++)
#pragma unroll
        for (int j = 0; j < 8; j++) acc[i][j] = 0.f;
    for (int k0 = 0; k0 < H_; k0 += BK) {
        __syncthreads();
#pragma unroll
        for (int r = 0; r < 2; r++) {
            int li = tid + r * 256;
            int tok = li >> 3, kg = li & 7;
            float4 v = *(const float4*)(enc + (size_t)(m0 + tok) * H_ + k0 + kg * 4);
            As[(kg * 4 + 0) * ASTR + tok] = v.x;
            As[(kg * 4 + 1) * ASTR + tok] = v.y;
            As[(kg * 4 + 2) * ASTR + tok] = v.z;
            As[(kg * 4 + 3) * ASTR + tok] = v.w;
        }
#pragma unroll
        for (int r = 0; r < 4; r++) {
            int li = tid + r * 256;
            int h = li >> 3, kg = li & 7;
            float4 v = *(const float4*)(Wk + (size_t)(h0 + h) * H_ + k0 + kg * 4);
            Bs[(kg * 4 + 0) * BSTR + h] = v.x;
            Bs[(kg * 4 + 1) * BSTR + h] = v.y;
            Bs[(kg * 4 + 2) * BSTR + h] = v.z;
            Bs[(kg * 4 + 3) * BSTR + h] = v.w;
        }
        __syncthreads();
#pragma unroll
        for (int kk = 0; kk < BK; kk++) {
            float4 a4 = *(const float4*)&As[kk * ASTR + ty * 4];
            float4 b4a = *(const float4*)&Bs[kk * BSTR + tx * 4];
            float4 b4b = *(const float4*)&Bs[kk * BSTR + 64 + tx * 4];
            float av[4] = {a4.x, a4.y, a4.z, a4.w};
            float bv[8] = {b4a.x, b4a.y, b4a.z, b4a.w, b4b.x, b4b.y, b4b.z, b4b.w};
#pragma unroll
            for (int i = 0; i < 4; i++)
#pragma unroll
                for (int j = 0; j < 8; j++) acc[i][j] += av[i] * bv[j];
        }
    }
    float wv[8], kqv[8];
#pragma unroll
    for (int j = 0; j < 8; j++) {
        int hl = (j < 4) ? (tx * 4 + j) : (64 + tx * 4 + (j - 4));
        wv[j] = wout_s[hl];
        kqv[j] = kq_s[hl];
    }
#pragma unroll
    for (int i = 0; i < 4; i++) {
        float s = 0.f;
#pragma unroll
        for (int j = 0; j < 8; j++) s += wv[j] * tanhf(acc[i][j] + kqv[j]);
#pragma unroll
        for (int m = 1; m < 16; m <<= 1) s += __shfl_xor(s, m, 64);
        if (tx == 0) atomicAdd(&score[m0 + ty * 4 + i], s);
    }
}
// --------------------------------------------------------------------------

__global__ __launch_bounds__(256) void softmax_kernel(float* __restrict__ score) {
    int b = blockIdx.x, tid = threadIdx.x;
    float* s = score + b * T_;
    __shared__ float red[8];
    float v[8];
    float mx = -1e30f;
#pragma unroll
    for (int i = 0; i < 8; i++) {
        v[i] = s[tid + i * 256];
        mx = fmaxf(mx, v[i]);
    }
#pragma unroll
    for (int m = 32; m >= 1; m >>= 1) mx = fmaxf(mx, __shfl_xor(mx, m, 64));
    if ((tid & 63) == 0) red[tid >> 6] = mx;
    __syncthreads();
    mx = fmaxf(fmaxf(red[0], red[1]), fmaxf(red[2], red[3]));
    float sum = 0.f;
#pragma unroll
    for (int i = 0; i < 8; i++) {
        v[i] = __expf(v[i] - mx);
        sum += v[i];
    }
#pragma unroll
    for (int m = 32; m >= 1; m >>= 1) sum += __shfl_xor(sum, m, 64);
    if ((tid & 63) == 0) red[4 + (tid >> 6)] = sum;
    __syncthreads();
    sum = red[4] + red[5] + red[6] + red[7];
    float inv = 1.f / sum;
#pragma unroll
    for (int i = 0; i < 8; i++) s[tid + i * 256] = v[i] * inv;
}

// ---- context, two-stage, NO atomics. partial ALIASES encb (dead after score). ----
__global__ __launch_bounds__(256) void ctx_partial(const float* __restrict__ enc,
                                                   const float* __restrict__ attn,
                                                   float* __restrict__ partial) {
    int ts = blockIdx.x, b = blockIdx.y;
    const float* e = enc + (size_t)b * T_ * H_ + (size_t)ts * 64 * H_ + threadIdx.x * 4;
    const float* a = attn + b * T_ + ts * 64;
    float4 acc = {0.f, 0.f, 0.f, 0.f};
#pragma unroll 4
    for (int t = 0; t < 64; t++) {
        float av = a[t];
        float4 v = *(const float4*)(e + (size_t)t * H_);
        acc.x += av * v.x; acc.y += av * v.y; acc.z += av * v.z; acc.w += av * v.w;
    }
    *(float4*)(partial + ((size_t)ts * B_ + b) * H_ + threadIdx.x * 4) = acc;
}

__global__ __launch_bounds__(256) void ctx_reduce(const float* __restrict__ partial,
                                                  float* __restrict__ out) {
    int b = blockIdx.x;
    int h = threadIdx.x * 4;
    float4 acc = {0.f, 0.f, 0.f, 0.f};
#pragma unroll
    for (int ts = 0; ts < 32; ts++) {
        float4 v = *(const float4*)(partial + ((size_t)ts * B_ + b) * H_ + h);
        acc.x += v.x; acc.y += v.y; acc.z += v.z; acc.w += v.w;
    }
    *(float4*)(out + (size_t)b * H_ + h) = acc;
}

// legacy atomic context (fallback path only)
__global__ __launch_bounds__(256) void context_kernel(const float* __restrict__ enc,
                                                      const float* __restrict__ attn,
                                                      float* __restrict__ out) {
    int ts = blockIdx.x, b = blockIdx.y;
    const float* e = enc + (size_t)b * T_ * H_ + (size_t)ts * 64 * H_ + threadIdx.x * 4;
    const float* a = attn + b * T_ + ts * 64;
    float4 acc = {0.f, 0.f, 0.f, 0.f};
#pragma unroll 4
    for (int t = 0; t < 64; t++) {
        float av = a[t];
        float4 v = *(const float4*)(e + (size_t)t * H_);
        acc.x += av * v.x; acc.y += av * v.y; acc.z += av * v.z; acc.w += av * v.w;
    }
    float* o = out + b * H_ + threadIdx.x * 4;
    atomicAdd(o + 0, acc.x);
    atomicAdd(o + 1, acc.y);
    atomicAdd(o + 2, acc.z);
    atomicAdd(o + 3, acc.w);
}

extern "C" void kernel_launch(void* const* d_in, const int* in_sizes, int n_in,
                              void* d_out, int out_size, void* d_ws, size_t ws_size,
                              hipStream_t stream) {
    const float* enc = (const float*)d_in[0];
    const float* dec = (const float*)d_in[1];
    const float* Wk = (const float*)d_in[2];
    const float* bk = (const float*)d_in[3];
    const float* Wq = (const float*)d_in[4];
    const float* bq = (const float*)d_in[5];
    const float* Wout = (const float*)d_in[6];
    // d_in[7] = bout: cancels under softmax. d_in[8] = inputs: unused.
    float* out = (float*)d_out;

    const size_t encb_bytes = (size_t)B_ * T_ * H_ * 2;   // 128 MiB
    const size_t wkb_bytes = (size_t)H_ * H_ * 2;         // 2 MiB
    const size_t kq_bytes = (size_t)B_ * H_ * 4;
    const size_t score_bytes = (size_t)B_ * T_ * 4;
    const size_t need_old = encb_bytes + wkb_bytes + kq_bytes + score_bytes;

    if (ws_size >= need_old) {
        __bf16* encb = (__bf16*)d_ws;
        __bf16* Wkb = (__bf16*)((char*)d_ws + encb_bytes);
        float* kq = (float*)((char*)d_ws + encb_bytes + wkb_bytes);
        float* score = kq + B_ * H_;
        float* partial = (float*)d_ws;  // aliases encb: dead after score_mfma

        convert_kernel<<<(B_ * T_ * H_) / 2048, 256, 0, stream>>>(enc, encb);
        convert_kernel<<<(H_ * H_) / 2048, 256, 0, stream>>>(Wk, Wkb);
        q_kernel<<<dim3(B_, 4), 256, 0, stream>>>(dec, Wq, bq, bk, kq);
        zero_kernel<<<(B_ * T_ + 255) / 256, 256, 0, stream>>>(score, B_ * T_);
        score_mfma<<<dim3(8, 256), 512, 0, stream>>>(encb, Wkb, kq, Wout, score);
        softmax_kernel<<<B_, 256, 0, stream>>>(score);
        ctx_partial<<<dim3(32, B_), 256, 0, stream>>>(enc, score, partial);
        ctx_reduce<<<B_, 256, 0, stream>>>(partial, out);
    } else {
        float* kq = (float*)d_ws;
        float* score = kq + B_ * H_;
        q_kernel<<<dim3(B_, 4), 256, 0, stream>>>(dec, Wq, bq, bk, kq);
        zero_kernel<<<(B_ * T_ + 255) / 256, 256, 0, stream>>>(score, B_ * T_);
        zero_kernel<<<(B_ * H_ + 255) / 256, 256, 0, stream>>>(out, B_ * H_);
        score_fp32<<<dim3(1024, 8), 256, 0, stream>>>(enc, Wk, kq, Wout, score);
        softmax_kernel<<<B_, 256, 0, stream>>>(score);
        context_kernel<<<dim3(32, B_), 256, 0, stream>>>(enc, score, out);
    }
}

// Round 14
// 709.375 us; speedup vs baseline: 1.0654x; 1.0654x over previous
//
#include <hip/hip_runtime.h>
#include <cmath>
#include <stdint.h>

#define B_ 32
#define T_ 2048
#define H_ 1024

typedef __attribute__((ext_vector_type(8))) __bf16 bf16x8;
typedef __attribute__((ext_vector_type(4))) float f32x4;

__device__ inline void async_copy16(const void* g, void* l) {
    __builtin_amdgcn_global_load_lds((const __attribute__((address_space(1))) uint32_t*)g,
                                     (__attribute__((address_space(3))) uint32_t*)l, 16, 0, 0);
}

__device__ inline float fast_tanh(float x) {
    float e = __expf(2.f * x);
    return 1.f - 2.f / (e + 1.f);
}

__global__ __launch_bounds__(256) void zero_kernel(float* __restrict__ p, int n) {
    int i = blockIdx.x * 256 + threadIdx.x;
    if (i < n) p[i] = 0.f;
}

// fp32 -> bf16 for BOTH enc (32768 blocks) and Wk (512 blocks) in one launch.
__global__ __launch_bounds__(256) void convert_all(const float* __restrict__ enc,
                                                   __bf16* __restrict__ encb,
                                                   const float* __restrict__ Wk,
                                                   __bf16* __restrict__ Wkb) {
    const int nb_enc = (B_ * T_ * H_) / 2048;  // 32768
    int blk = blockIdx.x;
    const float* in;
    __bf16* out;
    size_t base;
    if (blk < nb_enc) {
        in = enc; out = encb; base = (size_t)blk * 2048;
    } else {
        in = Wk; out = Wkb; base = (size_t)(blk - nb_enc) * 2048;
    }
    size_t i = base + (size_t)threadIdx.x * 8;
    const float4* p = (const float4*)(in + i);
    float4 v0 = p[0], v1 = p[1];
    bf16x8 o;
    o[0] = (__bf16)v0.x; o[1] = (__bf16)v0.y; o[2] = (__bf16)v0.z; o[3] = (__bf16)v0.w;
    o[4] = (__bf16)v1.x; o[5] = (__bf16)v1.y; o[6] = (__bf16)v1.z; o[7] = (__bf16)v1.w;
    *(bf16x8*)(out + i) = o;
}

// kq[b,h] = sum_j Wq[h,j]*dec[b,j] + bq[h] + bk[h]; ALSO zeros score
// (grid (32,4) = 128 blocks x 512 elems = 65536 = B_*T_).
__global__ __launch_bounds__(256) void q_kernel(const float* __restrict__ dec,
                                                const float* __restrict__ Wq,
                                                const float* __restrict__ bq,
                                                const float* __restrict__ bk,
                                                float* __restrict__ kq,
                                                float* __restrict__ score) {
    int b = blockIdx.x;
    int hc = blockIdx.y;
    {   // fold-in: zero score
        int lin = blockIdx.y * 32 + blockIdx.x;          // 0..127
        int z = lin * 512 + threadIdx.x * 2;
        score[z] = 0.f;
        score[z + 1] = 0.f;
    }
    __shared__ float ds[H_];
    for (int i = threadIdx.x; i < H_; i += 256) ds[i] = dec[b * H_ + i];
    __syncthreads();
    int h = hc * 256 + threadIdx.x;
    const float4* w = (const float4*)(Wq + (size_t)h * H_);
    float acc = 0.f;
#pragma unroll 8
    for (int j = 0; j < H_ / 4; j++) {
        float4 v = w[j];
        acc += v.x * ds[4 * j] + v.y * ds[4 * j + 1] + v.z * ds[4 * j + 2] + v.w * ds[4 * j + 3];
    }
    kq[b * H_ + h] = acc + bq[h] + bk[h];
}

// MFMA score GEMM: score[b,t] += sum_h Wout[h]*tanh(enc[t,:]·Wk[h,:] + kq[b,h])
//
// EXACT round-2 structure (measured 266 us — session best; r9's 2-block/CU
// diet REGRESSED to 320 us: work-per-barrier-bound, not occupancy-bound).
// 256x256 tile, BK=32, 8 waves 2Mx4N, per-wave 128x64 = 2x4x4 16x16 frags.
// 3 LDS buffers x 32 KB = 96 KB; stage K-tile j+2 while computing tile j.
// ONE s_barrier + counted vmcnt(4) per boundary (never 0 until the tail).
// (512,2): 256-reg cap — acc(128)+~90 VGPR fit unspilled (r7: (512,4) spilled).
__global__ __launch_bounds__(512, 2) void score_mfma(const __bf16* __restrict__ encb,
                                                     const __bf16* __restrict__ Wkb,
                                                     const float* __restrict__ kq,
                                                     const float* __restrict__ Wout,
                                                     float* __restrict__ score) {
    // per buffer: A = 1024 chunks (4 kg x 256 rows) x 16B, B = same; 32 KB
    __shared__ __align__(16) __bf16 lds[3][16384];

    // XCD-aware bijective remap: gridDim=(4,256), lin%8 = XCD. XCD x owns
    // m-blocks [x*32, x*32+32) x all 4 n-blocks -> encb panel L2-resident.
    const int lin = blockIdx.x + 4 * blockIdx.y;
    const int xcd = lin & 7;
    const int idx = lin >> 3;              // 0..127
    const int mblk = xcd * 32 + (idx >> 2);
    const int nblk = idx & 3;
    const int m0 = mblk * 256;
    const int h0 = nblk * 256;
    const int b = m0 >> 11;                // 2048 tokens per b; 256 | 2048

    const int tid = threadIdx.x;
    const int lane = tid & 63;
    const int w = tid >> 6;                // 0..7
    const int wm = w >> 2;                 // 0..1  (128-row half)
    const int wn = w & 3;                  // 0..3  (64-col slice)
    const int q4 = lane >> 4, l15 = lane & 15;

    // ---- staging slots: 2048 chunks/buffer, 4 loads/thread ----
    const int rowS = tid & 255;
    const int kgS = tid >> 8;              // 0 or 1, wave-uniform (64|256)
    const __bf16* gA0 = encb + (size_t)(m0 + rowS) * H_ + kgS * 8;
    const __bf16* gA1 = gA0 + 16;          // kg+2 -> +16 elements
    const __bf16* gB0 = Wkb + (size_t)(h0 + rowS) * H_ + kgS * 8;
    const __bf16* gB1 = gB0 + 16;
    const int sA0 = (w * 64) * 8;          // wave-uniform LDS element offsets
    const int sA1 = sA0 + 4096;            // +512 chunks
    const int sB0 = sA0 + 8192;            // B region starts at chunk 1024
    const int sB1 = sB0 + 4096;

    f32x4 acc[2][4][4];
#pragma unroll
    for (int g = 0; g < 2; g++)
#pragma unroll
        for (int i = 0; i < 4; i++)
#pragma unroll
            for (int jj = 0; jj < 4; jj++) acc[g][i][jj] = (f32x4){0.f, 0.f, 0.f, 0.f};

#define STAGE(jj)                                      \
    do {                                               \
        __bf16* Ld = &lds[(jj) % 3][0];                \
        const int kk = (jj) * 32;                      \
        async_copy16(gA0 + kk, Ld + sA0);              \
        async_copy16(gA1 + kk, Ld + sA1);              \
        async_copy16(gB0 + kk, Ld + sB0);              \
        async_copy16(gB1 + kk, Ld + sB1);              \
    } while (0)

    // prologue: tiles 0 and 1 in flight; wait tile 0 (4 newest may remain)
    STAGE(0);
    STAGE(1);
    asm volatile("s_waitcnt vmcnt(4)" ::: "memory");
    __builtin_amdgcn_s_barrier();
    __builtin_amdgcn_sched_barrier(0);

    for (int j = 0; j < 32; ++j) {
        if (j > 0) {
            if (j < 31) {
                asm volatile("s_waitcnt vmcnt(4)" ::: "memory");
            } else {
                asm volatile("s_waitcnt vmcnt(0)" ::: "memory");
            }
            __builtin_amdgcn_s_barrier();
            __builtin_amdgcn_sched_barrier(0);
        }
        const __bf16* L = &lds[j % 3][0];
        if (j < 30) STAGE(j + 2);

        // B frags: 4 x ds_read_b128 (chunk 1024 + q4*256 + wn*64 + nf*16 + l15)
        bf16x8 bfr[4];
#pragma unroll
        for (int nf = 0; nf < 4; nf++)
            bfr[nf] = *(const bf16x8*)(L + 8192 +
                                       (size_t)(q4 * 256 + wn * 64 + nf * 16 + l15) * 8);
        // A group 0 (rows wm*128 + 0..63), 16 MFMA; then group 1 (rows +64..127)
        bf16x8 afr[4];
#pragma unroll
        for (int mf = 0; mf < 4; mf++)
            afr[mf] = *(const bf16x8*)(L +
                                       (size_t)(q4 * 256 + wm * 128 + mf * 16 + l15) * 8);
        __builtin_amdgcn_s_setprio(1);
#pragma unroll
        for (int mf = 0; mf < 4; mf++)
#pragma unroll
            for (int nf = 0; nf < 4; nf++)
                acc[0][mf][nf] =
                    __builtin_amdgcn_mfma_f32_16x16x32_bf16(afr[mf], bfr[nf], acc[0][mf][nf], 0, 0, 0);
        __builtin_amdgcn_s_setprio(0);
#pragma unroll
        for (int mf = 0; mf < 4; mf++)
            afr[mf] = *(const bf16x8*)(L +
                                       (size_t)(q4 * 256 + wm * 128 + 64 + mf * 16 + l15) * 8);
        __builtin_amdgcn_s_setprio(1);
#pragma unroll
        for (int mf = 0; mf < 4; mf++)
#pragma unroll
            for (int nf = 0; nf < 4; nf++)
                acc[1][mf][nf] =
                    __builtin_amdgcn_mfma_f32_16x16x32_bf16(afr[mf], bfr[nf], acc[1][mf][nf], 0, 0, 0);
        __builtin_amdgcn_s_setprio(0);
    }
#undef STAGE

    // epilogue: per row, sum_h wout[h]*tanh(K + kq) over this wave's 64 columns
    float wv[4], kqv[4];
#pragma unroll
    for (int nf = 0; nf < 4; nf++) {
        int h = h0 + wn * 64 + nf * 16 + l15;
        wv[nf] = Wout[h];
        kqv[nf] = kq[b * H_ + h];
    }
#pragma unroll
    for (int g = 0; g < 2; g++) {
#pragma unroll
        for (int mf = 0; mf < 4; mf++) {
#pragma unroll
            for (int r = 0; r < 4; r++) {
                float s = 0.f;
#pragma unroll
                for (int nf = 0; nf < 4; nf++)
                    s += wv[nf] * fast_tanh(acc[g][mf][nf][r] + kqv[nf]);
#pragma unroll
                for (int m = 1; m < 16; m <<= 1) s += __shfl_xor(s, m, 64);
                if (l15 == 0)
                    atomicAdd(&score[m0 + wm * 128 + g * 64 + mf * 16 + q4 * 4 + r], s);
            }
        }
    }
}

// ---------- fp32 fallback score path (used only if ws too small) ----------
#define BK 32
#define ASTR 68
#define BSTR 132
__global__ __launch_bounds__(256) void score_fp32(const float* __restrict__ enc,
                                                  const float* __restrict__ Wk,
                                                  const float* __restrict__ kq,
                                                  const float* __restrict__ Wout,
                                                  float* __restrict__ score) {
    __shared__ __align__(16) float As[BK * ASTR];
    __shared__ __align__(16) float Bs[BK * BSTR];
    __shared__ float wout_s[128];
    __shared__ float kq_s[128];
    const int m0 = blockIdx.x * 64;
    const int h0 = blockIdx.y * 128;
    const int b = m0 >> 11;
    const int tid = threadIdx.x;
    const int tx = tid & 15;
    const int ty = tid >> 4;
    if (tid < 128) {
        wout_s[tid] = Wout[h0 + tid];
        kq_s[tid] = kq[b * H_ + h0 + tid];
    }
    float acc[4][8];
#pragma unroll
    for (int i = 0; i < 4; i++)
#pragma unroll
        for (int j = 0; j < 8; j++) acc[i][j] = 0.f;
    for (int k0 = 0; k0 < H_; k0 += BK) {
        __syncthreads();
#pragma unroll
        for (int r = 0; r < 2; r++) {
            int li = tid + r * 256;
            int tok = li >> 3, kg = li & 7;
            float4 v = *(const float4*)(enc + (size_t)(m0 + tok) * H_ + k0 + kg * 4);
            As[(kg * 4 + 0) * ASTR + tok] = v.x;
            As[(kg * 4 + 1) * ASTR + tok] = v.y;
            As[(kg * 4 + 2) * ASTR + tok] = v.z;
            As[(kg * 4 + 3) * ASTR + tok] = v.w;
        }
#pragma unroll
        for (int r = 0; r < 4; r++) {
            int li = tid + r * 256;
            int h = li >> 3, kg = li & 7;
            float4 v = *(const float4*)(Wk + (size_t)(h0 + h) * H_ + k0 + kg * 4);
            Bs[(kg * 4 + 0) * BSTR + h] = v.x;
            Bs[(kg * 4 + 1) * BSTR + h] = v.y;
            Bs[(kg * 4 + 2) * BSTR + h] = v.z;
            Bs[(kg * 4 + 3) * BSTR + h] = v.w;
        }
        __syncthreads();
#pragma unroll
        for (int kk = 0; kk < BK; kk++) {
            float4 a4 = *(const float4*)&As[kk * ASTR + ty * 4];
            float4 b4a = *(const float4*)&Bs[kk * BSTR + tx * 4];
            float4 b4b = *(const float4*)&Bs[kk * BSTR + 64 + tx * 4];
            float av[4] = {a4.x, a4.y, a4.z, a4.w};
            float bv[8] = {b4a.x, b4a.y, b4a.z, b4a.w, b4b.x, b4b.y, b4b.z, b4b.w};
#pragma unroll
            for (int i = 0; i < 4; i++)
#pragma unroll
                for (int j = 0; j < 8; j++) acc[i][j] += av[i] * bv[j];
        }
    }
    float wv[8], kqv[8];
#pragma unroll
    for (int j = 0; j < 8; j++) {
        int hl = (j < 4) ? (tx * 4 + j) : (64 + tx * 4 + (j - 4));
        wv[j] = wout_s[hl];
        kqv[j] = kq_s[hl];
    }
#pragma unroll
    for (int i = 0; i < 4; i++) {
        float s = 0.f;
#pragma unroll
        for (int j = 0; j < 8; j++) s += wv[j] * tanhf(acc[i][j] + kqv[j]);
#pragma unroll
        for (int m = 1; m < 16; m <<= 1) s += __shfl_xor(s, m, 64);
        if (tx == 0) atomicAdd(&score[m0 + ty * 4 + i], s);
    }
}
// --------------------------------------------------------------------------

__global__ __launch_bounds__(256) void softmax_kernel(float* __restrict__ score) {
    int b = blockIdx.x, tid = threadIdx.x;
    float* s = score + b * T_;
    __shared__ float red[8];
    float v[8];
    float mx = -1e30f;
#pragma unroll
    for (int i = 0; i < 8; i++) {
        v[i] = s[tid + i * 256];
        mx = fmaxf(mx, v[i]);
    }
#pragma unroll
    for (int m = 32; m >= 1; m >>= 1) mx = fmaxf(mx, __shfl_xor(mx, m, 64));
    if ((tid & 63) == 0) red[tid >> 6] = mx;
    __syncthreads();
    mx = fmaxf(fmaxf(red[0], red[1]), fmaxf(red[2], red[3]));
    float sum = 0.f;
#pragma unroll
    for (int i = 0; i < 8; i++) {
        v[i] = __expf(v[i] - mx);
        sum += v[i];
    }
#pragma unroll
    for (int m = 32; m >= 1; m >>= 1) sum += __shfl_xor(sum, m, 64);
    if ((tid & 63) == 0) red[4 + (tid >> 6)] = sum;
    __syncthreads();
    sum = red[4] + red[5] + red[6] + red[7];
    float inv = 1.f / sum;
#pragma unroll
    for (int i = 0; i < 8; i++) s[tid + i * 256] = v[i] * inv;
}

// ---- context, two-stage, NO atomics. partial ALIASES encb (dead after
// score_mfma) — this alias PASSED in round 8. ----
__global__ __launch_bounds__(256) void ctx_partial(const float* __restrict__ enc,
                                                   const float* __restrict__ attn,
                                                   float* __restrict__ partial) {
    int ts = blockIdx.x, b = blockIdx.y;
    const float* e = enc + (size_t)b * T_ * H_ + (size_t)ts * 64 * H_ + threadIdx.x * 4;
    const float* a = attn + b * T_ + ts * 64;
    float4 acc = {0.f, 0.f, 0.f, 0.f};
#pragma unroll 4
    for (int t = 0; t < 64; t++) {
        float av = a[t];
        float4 v = *(const float4*)(e + (size_t)t * H_);
        acc.x += av * v.x; acc.y += av * v.y; acc.z += av * v.z; acc.w += av * v.w;
    }
    *(float4*)(partial + ((size_t)ts * B_ + b) * H_ + threadIdx.x * 4) = acc;
}

__global__ __launch_bounds__(256) void ctx_reduce(const float* __restrict__ partial,
                                                  float* __restrict__ out) {
    int b = blockIdx.x;
    int h = threadIdx.x * 4;
    float4 acc = {0.f, 0.f, 0.f, 0.f};
#pragma unroll
    for (int ts = 0; ts < 32; ts++) {
        float4 v = *(const float4*)(partial + ((size_t)ts * B_ + b) * H_ + h);
        acc.x += v.x; acc.y += v.y; acc.z += v.z; acc.w += v.w;
    }
    *(float4*)(out + (size_t)b * H_ + h) = acc;
}

// legacy atomic context (fallback path only)
__global__ __launch_bounds__(256) void context_kernel(const float* __restrict__ enc,
                                                      const float* __restrict__ attn,
                                                      float* __restrict__ out) {
    int ts = blockIdx.x, b = blockIdx.y;
    const float* e = enc + (size_t)b * T_ * H_ + (size_t)ts * 64 * H_ + threadIdx.x * 4;
    const float* a = attn + b * T_ + ts * 64;
    float4 acc = {0.f, 0.f, 0.f, 0.f};
#pragma unroll 4
    for (int t = 0; t < 64; t++) {
        float av = a[t];
        float4 v = *(const float4*)(e + (size_t)t * H_);
        acc.x += av * v.x; acc.y += av * v.y; acc.z += av * v.z; acc.w += av * v.w;
    }
    float* o = out + b * H_ + threadIdx.x * 4;
    atomicAdd(o + 0, acc.x);
    atomicAdd(o + 1, acc.y);
    atomicAdd(o + 2, acc.z);
    atomicAdd(o + 3, acc.w);
}

extern "C" void kernel_launch(void* const* d_in, const int* in_sizes, int n_in,
                              void* d_out, int out_size, void* d_ws, size_t ws_size,
                              hipStream_t stream) {
    const float* enc = (const float*)d_in[0];
    const float* dec = (const float*)d_in[1];
    const float* Wk = (const float*)d_in[2];
    const float* bk = (const float*)d_in[3];
    const float* Wq = (const float*)d_in[4];
    const float* bq = (const float*)d_in[5];
    const float* Wout = (const float*)d_in[6];
    // d_in[7] = bout: cancels under softmax. d_in[8] = inputs: unused.
    float* out = (float*)d_out;

    const size_t encb_bytes = (size_t)B_ * T_ * H_ * 2;   // 128 MiB
    const size_t wkb_bytes = (size_t)H_ * H_ * 2;         // 2 MiB
    const size_t kq_bytes = (size_t)B_ * H_ * 4;
    const size_t score_bytes = (size_t)B_ * T_ * 4;
    const size_t need_old = encb_bytes + wkb_bytes + kq_bytes + score_bytes;

    if (ws_size >= need_old) {
        __bf16* encb = (__bf16*)d_ws;
        __bf16* Wkb = (__bf16*)((char*)d_ws + encb_bytes);
        float* kq = (float*)((char*)d_ws + encb_bytes + wkb_bytes);
        float* score = kq + B_ * H_;
        float* partial = (float*)d_ws;  // aliases encb: dead after score_mfma

        convert_all<<<(B_ * T_ * H_) / 2048 + (H_ * H_) / 2048, 256, 0, stream>>>(enc, encb, Wk, Wkb);
        q_kernel<<<dim3(B_, 4), 256, 0, stream>>>(dec, Wq, bq, bk, kq, score);
        score_mfma<<<dim3(4, 256), 512, 0, stream>>>(encb, Wkb, kq, Wout, score);
        softmax_kernel<<<B_, 256, 0, stream>>>(score);
        ctx_partial<<<dim3(32, B_), 256, 0, stream>>>(enc, score, partial);
        ctx_reduce<<<B_, 256, 0, stream>>>(partial, out);
    } else {
        float* kq = (float*)d_ws;
        float* score = kq + B_ * H_;
        q_kernel<<<dim3(B_, 4), 256, 0, stream>>>(dec, Wq, bq, bk, kq, score);
        zero_kernel<<<(B_ * H_ + 255) / 256, 256, 0, stream>>>(out, B_ * H_);
        score_fp32<<<dim3(1024, 8), 256, 0, stream>>>(enc, Wk, kq, Wout, score);
        softmax_kernel<<<B_, 256, 0, stream>>>(score);
        context_kernel<<<dim3(32, B_), 256, 0, stream>>>(enc, score, out);
    }
}